// Round 2
// baseline (2265.030 us; speedup 1.0000x reference)
//
#include <hip/hip_runtime.h>
#include <stddef.h>

// ---------------- problem constants ----------------
#define MDIM 8192      // B*S = 4*2048
#define NDIM 16384     // D_OUT
#define KDIM 4096      // D_IN

#define BM 128
#define BN 128
#define BK 64
#define THREADS 256

typedef __attribute__((ext_vector_type(4))) float  f32x4;
typedef __attribute__((ext_vector_type(8))) short  short8;
typedef __attribute__((ext_vector_type(4))) short  short4v;

// fp32 -> bf16 round-to-nearest-even
static __device__ inline short f32_to_bf16(float f) {
    unsigned int u = __builtin_bit_cast(unsigned int, f);
    unsigned int r = 0x7FFFu + ((u >> 16) & 1u);
    u += r;
    return (short)(u >> 16);
}

// Convert n8*8 fp32 values to bf16 (grid-stride), optionally * scale_ptr[0].
__global__ void cvt_f32_to_bf16(const float* __restrict__ src,
                                short* __restrict__ dst,
                                long long n8,
                                const float* __restrict__ scale_ptr,
                                int use_scale) {
    float s = use_scale ? scale_ptr[0] : 1.0f;
    long long stride = (long long)gridDim.x * blockDim.x;
    for (long long i = (long long)blockIdx.x * blockDim.x + threadIdx.x;
         i < n8; i += stride) {
        const f32x4* p = (const f32x4*)(src + i * 8);
        f32x4 v0 = p[0];
        f32x4 v1 = p[1];
        short8 o;
#pragma unroll
        for (int j = 0; j < 4; ++j) {
            o[j]     = f32_to_bf16(v0[j] * s);
            o[j + 4] = f32_to_bf16(v1[j] * s);
        }
        *(short8*)(dst + i * 8) = o;
    }
}

// C[m][n] = sum_k A[m][k] * Bt[n][k] + bias[n]
// FUSED=false: A,Bt are pre-converted bf16 (short*), staged via global_load_lds.
// FUSED=true : Af,Btf are fp32 sources; reg-stage + convert + ds_write (no ws).
template <bool FUSED>
__global__ __launch_bounds__(THREADS) void gemm_bf16_bt_bias(
        const short* __restrict__ A,
        const short* __restrict__ Bt,
        const float* __restrict__ Af,
        const float* __restrict__ Btf,
        const float* __restrict__ scale_ptr,
        const float* __restrict__ bias,
        float* __restrict__ C) {
    __shared__ __attribute__((aligned(16))) short As[BM * BK];
    __shared__ __attribute__((aligned(16))) short Bs[BN * BK];

    const int tid  = threadIdx.x;
    const int lane = tid & 63;
    const int wave = tid >> 6;
    const int wr = wave >> 1;   // wave row (0..1), 64 rows each
    const int wc = wave & 1;    // wave col (0..1), 64 cols each

    // XCD-aware bijective swizzle: nwg = 8192, divisible by 8.
    const int ntn = NDIM / BN;                    // 128
    const int nwg = (MDIM / BM) * (NDIM / BN);    // 8192
    int bid = blockIdx.x;
    int swz = (bid & 7) * (nwg >> 3) + (bid >> 3);
    const int m0 = (swz / ntn) * BM;
    const int n0 = (swz % ntn) * BN;

    float xscale = 1.0f;
    if constexpr (FUSED) xscale = scale_ptr[0];

    f32x4 acc[4][4];
#pragma unroll
    for (int i = 0; i < 4; ++i)
#pragma unroll
        for (int j = 0; j < 4; ++j)
            acc[i][j] = (f32x4){0.f, 0.f, 0.f, 0.f};

    const int lrow = lane & 15;         // fragment row/col within 16
    const int lk   = (lane >> 4) * 8;   // k-offset of this lane's 8 elems

    for (int kt = 0; kt < KDIM; kt += BK) {
        // ---- stage A,B tiles: 128 rows x 64 cols bf16 = 1024 chunks of 16 B
        // chunk c: row = c/8, col = (c%8)*8. LDS linear => lane-contiguous.
        if constexpr (!FUSED) {
#pragma unroll
            for (int it = 0; it < 4; ++it) {
                int chunk = it * THREADS + tid;
                int row = chunk >> 3;
                int col = (chunk & 7) << 3;
                const short* gA = A + (size_t)(m0 + row) * KDIM + kt + col;
                const short* gB = Bt + (size_t)(n0 + row) * KDIM + kt + col;
                __builtin_amdgcn_global_load_lds(
                    (const __attribute__((address_space(1))) void*)gA,
                    (__attribute__((address_space(3))) void*)(As + chunk * 8),
                    16, 0, 0);
                __builtin_amdgcn_global_load_lds(
                    (const __attribute__((address_space(1))) void*)gB,
                    (__attribute__((address_space(3))) void*)(Bs + chunk * 8),
                    16, 0, 0);
            }
        } else {
#pragma unroll
            for (int it = 0; it < 4; ++it) {
                int chunk = it * THREADS + tid;
                int row = chunk >> 3;
                int col = (chunk & 7) << 3;
                const f32x4* gA = (const f32x4*)(Af + (size_t)(m0 + row) * KDIM + kt + col);
                const f32x4* gB = (const f32x4*)(Btf + (size_t)(n0 + row) * KDIM + kt + col);
                f32x4 a0 = gA[0], a1 = gA[1];
                f32x4 b0 = gB[0], b1 = gB[1];
                short8 ao, bo;
#pragma unroll
                for (int j = 0; j < 4; ++j) {
                    ao[j]     = f32_to_bf16(a0[j] * xscale);
                    ao[j + 4] = f32_to_bf16(a1[j] * xscale);
                    bo[j]     = f32_to_bf16(b0[j]);
                    bo[j + 4] = f32_to_bf16(b1[j]);
                }
                *(short8*)(As + chunk * 8) = ao;
                *(short8*)(Bs + chunk * 8) = bo;
            }
        }
        __syncthreads();   // drains vmcnt+lgkmcnt then barrier

        // ---- compute: 2 k-subtiles of 32 ----
#pragma unroll
        for (int ks = 0; ks < 2; ++ks) {
            short8 af[4], bf[4];
#pragma unroll
            for (int mi = 0; mi < 4; ++mi)
                af[mi] = *(const short8*)(As + (wr * 64 + mi * 16 + lrow) * BK + ks * 32 + lk);
#pragma unroll
            for (int ni = 0; ni < 4; ++ni)
                bf[ni] = *(const short8*)(Bs + (wc * 64 + ni * 16 + lrow) * BK + ks * 32 + lk);
#pragma unroll
            for (int mi = 0; mi < 4; ++mi)
#pragma unroll
                for (int ni = 0; ni < 4; ++ni)
                    acc[mi][ni] = __builtin_amdgcn_mfma_f32_16x16x32_bf16(
                        af[mi], bf[ni], acc[mi][ni], 0, 0, 0);
        }
        __syncthreads();
    }

    // ---- epilogue: add bias, store fp32 ----
    const int crow = (lane >> 4) * 4;
    const int ccol = lane & 15;
#pragma unroll
    for (int ni = 0; ni < 4; ++ni) {
        int col = n0 + wc * 64 + ni * 16 + ccol;
        float bv = bias[col];
#pragma unroll
        for (int mi = 0; mi < 4; ++mi) {
            int row = m0 + wr * 64 + mi * 16 + crow;
#pragma unroll
            for (int r = 0; r < 4; ++r)
                C[(size_t)(row + r) * NDIM + col] = acc[mi][ni][r] + bv;
        }
    }
}

extern "C" void kernel_launch(void* const* d_in, const int* in_sizes, int n_in,
                              void* d_out, int out_size, void* d_ws, size_t ws_size,
                              hipStream_t stream) {
    const float* x     = (const float*)d_in[0];   // 8192*4096
    const float* w     = (const float*)d_in[1];   // 16384*4096
    const float* scale = (const float*)d_in[2];   // 1
    const float* bias  = (const float*)d_in[3];   // 16384
    float* out = (float*)d_out;

    const long long xN = (long long)MDIM * KDIM;  // 33,554,432
    const long long wN = (long long)NDIM * KDIM;  // 67,108,864
    const size_t needed = (size_t)(xN + wN) * sizeof(short);  // 192 MiB

    dim3 grid((MDIM / BM) * (NDIM / BN));   // 8192 blocks

    if (ws_size >= needed) {
        short* xb = (short*)d_ws;          // bf16 x*scale
        short* wb = xb + xN;               // bf16 W

        cvt_f32_to_bf16<<<2048, 256, 0, stream>>>(x, xb, xN / 8, scale, 1);
        cvt_f32_to_bf16<<<2048, 256, 0, stream>>>(w, wb, wN / 8, scale, 0);

        gemm_bf16_bt_bias<false><<<grid, THREADS, 0, stream>>>(
            xb, wb, nullptr, nullptr, nullptr, bias, out);
    } else {
        // workspace too small: fused conversion inside the GEMM (no scratch)
        gemm_bf16_bt_bias<true><<<grid, THREADS, 0, stream>>>(
            nullptr, nullptr, x, w, scale, bias, out);
    }
}

// Round 3
// 1714.078 us; speedup vs baseline: 1.3214x; 1.3214x over previous
//
#include <hip/hip_runtime.h>
#include <stddef.h>

// ---------------- problem constants ----------------
#define MDIM 8192      // B*S
#define NDIM 16384     // D_OUT
#define KDIM 4096      // D_IN

#define BM 256
#define BN 256
#define BK 64
#define THREADS 512
#define NTILES (KDIM / BK)   // 64

typedef __attribute__((ext_vector_type(4))) float  f32x4;
typedef __attribute__((ext_vector_type(8))) short  short8;

static __device__ __forceinline__ short f32_to_bf16(float f) {
    unsigned int u = __builtin_bit_cast(unsigned int, f);
    u += 0x7FFFu + ((u >> 16) & 1u);
    return (short)(u >> 16);
}

// ---- single conversion kernel: x*scale -> xb, w -> wb (both bf16) ----
__global__ void cvt_all(const float* __restrict__ x, const float* __restrict__ w,
                        const float* __restrict__ scale_ptr,
                        short* __restrict__ xb, short* __restrict__ wb) {
    const long long xC = (long long)MDIM * KDIM / 8;            // x chunks
    const long long tC = xC + (long long)NDIM * KDIM / 8;       // total
    const float s = scale_ptr[0];
    const long long stride = (long long)gridDim.x * blockDim.x;
    for (long long i = (long long)blockIdx.x * blockDim.x + threadIdx.x;
         i < tC; i += stride) {
        const float* src; short* dst; float m; long long j;
        if (i < xC) { src = x; dst = xb; m = s;    j = i; }
        else        { src = w; dst = wb; m = 1.0f; j = i - xC; }
        const f32x4* p = (const f32x4*)(src + j * 8);
        f32x4 v0 = p[0], v1 = p[1];
        short8 o;
#pragma unroll
        for (int q = 0; q < 4; ++q) {
            o[q]     = f32_to_bf16(v0[q] * m);
            o[q + 4] = f32_to_bf16(v1[q] * m);
        }
        *(short8*)(dst + j * 8) = o;
    }
}

// ---- 256x256 tile, 8-wave, 4-phase/K-tile, double-buffered, T2-swizzled ----
// LDS map: lds[buf][op(0=A,1=B)][half(128 rows)][128*64 bf16] = 128 KiB total.
// Swizzle: 16B-slot index XOR (row&7), applied on ds_read addr AND on the
// pre-swizzled global source (LDS dest stays linear for global_load_lds).
__global__ __launch_bounds__(THREADS, 2) void gemm256_bf16_bt_bias(
        const short* __restrict__ A,
        const short* __restrict__ Bt,
        const float* __restrict__ bias,
        float* __restrict__ C) {
    __shared__ __attribute__((aligned(16))) short lds[2][2][2][128 * 64];

    const int tid  = threadIdx.x;
    const int lane = tid & 63;
    const int wave = tid >> 6;      // 0..7
    const int wr   = wave >> 2;     // 0..1 : 128 output rows each
    const int wc   = wave & 3;      // 0..3 : 64 output cols each
    const int lrow = lane & 15;
    const int lkb  = (lane >> 4) * 16;        // byte offset of lane's k-slice
    const int rswz = (lrow & 7) << 4;         // T2 swizzle term

    // grid: 2048 blocks; XCD-bijective swizzle, then column-major (m fastest)
    int bid = blockIdx.x;
    int swz = (bid & 7) * (2048 / 8) + (bid >> 3);
    const int m0 = (swz & 31) << 8;           // m-tile * 256
    const int n0 = (swz >> 5) << 8;           // n-tile * 256

    // ---- staging: one 128x64 half-tile = 1024 x 16B chunks, 2 per thread ----
    auto stage = [&](int buf, int op, int half, int ktile,
                     const short* __restrict__ gsrc, int rowbase) {
        short* dst0 = &lds[buf][op][half][0];
        const long long kt = (long long)ktile * BK;
#pragma unroll
        for (int i = 0; i < 2; ++i) {
            int c = tid + i * THREADS;            // 0..1023
            int r = c >> 3;                       // row in half
            int slot = c & 7;                     // 16B slot in row
            const short* src = gsrc
                + (size_t)(rowbase + half * 128 + r) * KDIM
                + kt + ((slot ^ (r & 7)) << 3);   // pre-swizzled source col
            __builtin_amdgcn_global_load_lds(
                (const __attribute__((address_space(1))) void*)src,
                (__attribute__((address_space(3))) void*)(dst0 + c * 8),
                16, 0, 0);
        }
    };

    auto readA = [&](int buf, int mi, int ks) -> short8 {
        const char* base = (const char*)&lds[buf][0][wr][0];
        int boff = (mi * 16 + lrow) * 128 + ((ks * 64 + lkb) ^ rswz);
        return *(const short8*)(base + boff);
    };
    auto readB = [&](int buf, int ni, int ks) -> short8 {
        const char* base = (const char*)&lds[buf][1][wc >> 1][0];
        int boff = ((wc & 1) * 64 + ni * 16 + lrow) * 128 + ((ks * 64 + lkb) ^ rswz);
        return *(const short8*)(base + boff);
    };

    f32x4 acc[8][4];
#pragma unroll
    for (int i = 0; i < 8; ++i)
#pragma unroll
        for (int j = 0; j < 4; ++j)
            acc[i][j] = (f32x4){0.f, 0.f, 0.f, 0.f};

    // ---- prologue: tile0 complete + tile1.B in flight ----
    stage(0, 0, 0, 0, A,  m0);
    stage(0, 0, 1, 0, A,  m0);
    stage(0, 1, 0, 0, Bt, n0);
    stage(0, 1, 1, 0, Bt, n0);
    stage(1, 1, 0, 1, Bt, n0);
    stage(1, 1, 1, 1, Bt, n0);
    asm volatile("s_waitcnt vmcnt(4)" ::: "memory");
    __builtin_amdgcn_s_barrier();

#pragma unroll 2
    for (int t = 0; t < NTILES; ++t) {
        const int buf = t & 1, nbuf = buf ^ 1;
        const int tA = (t + 1 < NTILES) ? t + 1 : NTILES - 1;
        const int tB = (t + 2 < NTILES) ? t + 2 : NTILES - 1;

        // ---- P1: read ALL B frags + A m0-1; stage next A-half0 ----
        short8 bfr[4][2];
#pragma unroll
        for (int ni = 0; ni < 4; ++ni)
#pragma unroll
            for (int ks = 0; ks < 2; ++ks)
                bfr[ni][ks] = readB(buf, ni, ks);
        {
            short8 a0k0 = readA(buf, 0, 0), a0k1 = readA(buf, 0, 1);
            short8 a1k0 = readA(buf, 1, 0), a1k1 = readA(buf, 1, 1);
            stage(nbuf, 0, 0, tA, A, m0);
            __builtin_amdgcn_s_barrier();
            __builtin_amdgcn_s_setprio(1);
#pragma unroll
            for (int ni = 0; ni < 4; ++ni) {
                acc[0][ni] = __builtin_amdgcn_mfma_f32_16x16x32_bf16(a0k0, bfr[ni][0], acc[0][ni], 0, 0, 0);
                acc[0][ni] = __builtin_amdgcn_mfma_f32_16x16x32_bf16(a0k1, bfr[ni][1], acc[0][ni], 0, 0, 0);
                acc[1][ni] = __builtin_amdgcn_mfma_f32_16x16x32_bf16(a1k0, bfr[ni][0], acc[1][ni], 0, 0, 0);
                acc[1][ni] = __builtin_amdgcn_mfma_f32_16x16x32_bf16(a1k1, bfr[ni][1], acc[1][ni], 0, 0, 0);
            }
            __builtin_amdgcn_s_setprio(0);
            __builtin_amdgcn_s_barrier();
        }
        // ---- P2: read A m2-3; stage next A-half1 ----
        {
            short8 a0k0 = readA(buf, 2, 0), a0k1 = readA(buf, 2, 1);
            short8 a1k0 = readA(buf, 3, 0), a1k1 = readA(buf, 3, 1);
            stage(nbuf, 0, 1, tA, A, m0);
            __builtin_amdgcn_s_barrier();
            __builtin_amdgcn_s_setprio(1);
#pragma unroll
            for (int ni = 0; ni < 4; ++ni) {
                acc[2][ni] = __builtin_amdgcn_mfma_f32_16x16x32_bf16(a0k0, bfr[ni][0], acc[2][ni], 0, 0, 0);
                acc[2][ni] = __builtin_amdgcn_mfma_f32_16x16x32_bf16(a0k1, bfr[ni][1], acc[2][ni], 0, 0, 0);
                acc[3][ni] = __builtin_amdgcn_mfma_f32_16x16x32_bf16(a1k0, bfr[ni][0], acc[3][ni], 0, 0, 0);
                acc[3][ni] = __builtin_amdgcn_mfma_f32_16x16x32_bf16(a1k1, bfr[ni][1], acc[3][ni], 0, 0, 0);
            }
            __builtin_amdgcn_s_setprio(0);
            __builtin_amdgcn_s_barrier();
        }
        // ---- P3: read A m4-5; stage tile+2 B-half0 (B of buf fully read in P1) ----
        {
            short8 a0k0 = readA(buf, 4, 0), a0k1 = readA(buf, 4, 1);
            short8 a1k0 = readA(buf, 5, 0), a1k1 = readA(buf, 5, 1);
            stage(buf, 1, 0, tB, Bt, n0);
            __builtin_amdgcn_s_barrier();
            __builtin_amdgcn_s_setprio(1);
#pragma unroll
            for (int ni = 0; ni < 4; ++ni) {
                acc[4][ni] = __builtin_amdgcn_mfma_f32_16x16x32_bf16(a0k0, bfr[ni][0], acc[4][ni], 0, 0, 0);
                acc[4][ni] = __builtin_amdgcn_mfma_f32_16x16x32_bf16(a0k1, bfr[ni][1], acc[4][ni], 0, 0, 0);
                acc[5][ni] = __builtin_amdgcn_mfma_f32_16x16x32_bf16(a1k0, bfr[ni][0], acc[5][ni], 0, 0, 0);
                acc[5][ni] = __builtin_amdgcn_mfma_f32_16x16x32_bf16(a1k1, bfr[ni][1], acc[5][ni], 0, 0, 0);
            }
            __builtin_amdgcn_s_setprio(0);
            __builtin_amdgcn_s_barrier();
        }
        // ---- P4: read A m6-7; stage tile+2 B-half1; counted vmcnt(4) ----
        {
            short8 a0k0 = readA(buf, 6, 0), a0k1 = readA(buf, 6, 1);
            short8 a1k0 = readA(buf, 7, 0), a1k1 = readA(buf, 7, 1);
            stage(buf, 1, 1, tB, Bt, n0);
            __builtin_amdgcn_s_barrier();
            __builtin_amdgcn_s_setprio(1);
#pragma unroll
            for (int ni = 0; ni < 4; ++ni) {
                acc[6][ni] = __builtin_amdgcn_mfma_f32_16x16x32_bf16(a0k0, bfr[ni][0], acc[6][ni], 0, 0, 0);
                acc[6][ni] = __builtin_amdgcn_mfma_f32_16x16x32_bf16(a0k1, bfr[ni][1], acc[6][ni], 0, 0, 0);
                acc[7][ni] = __builtin_amdgcn_mfma_f32_16x16x32_bf16(a1k0, bfr[ni][0], acc[7][ni], 0, 0, 0);
                acc[7][ni] = __builtin_amdgcn_mfma_f32_16x16x32_bf16(a1k1, bfr[ni][1], acc[7][ni], 0, 0, 0);
            }
            __builtin_amdgcn_s_setprio(0);
            // tile t+1 fully landed; only tile t+2's two B half-tiles may fly
            asm volatile("s_waitcnt vmcnt(4)" ::: "memory");
            __builtin_amdgcn_s_barrier();
        }
    }

    // ---- epilogue: bias + store ----
    const int fq = (lane >> 4) * 4;
    const int fr = lane & 15;
#pragma unroll
    for (int ni = 0; ni < 4; ++ni) {
        int col = n0 + wc * 64 + ni * 16 + fr;
        float bv = bias[col];
#pragma unroll
        for (int mi = 0; mi < 8; ++mi) {
            int rowb = m0 + wr * 128 + mi * 16 + fq;
#pragma unroll
            for (int j = 0; j < 4; ++j)
                C[(size_t)(rowb + j) * NDIM + col] = acc[mi][ni][j] + bv;
        }
    }
}

// ---- fallback (small ws): round-2 fused 128^2 kernel, validated structure ----
__global__ __launch_bounds__(256) void gemm_fused128(
        const float* __restrict__ Af, const float* __restrict__ Btf,
        const float* __restrict__ scale_ptr, const float* __restrict__ bias,
        float* __restrict__ C) {
    __shared__ __attribute__((aligned(16))) short As[128 * 64];
    __shared__ __attribute__((aligned(16))) short Bs[128 * 64];
    const int tid = threadIdx.x, lane = tid & 63, wave = tid >> 6;
    const int wr = wave >> 1, wc = wave & 1;
    const int nwg = (MDIM / 128) * (NDIM / 128);
    int bid = blockIdx.x;
    int swz = (bid & 7) * (nwg >> 3) + (bid >> 3);
    const int m0 = (swz / (NDIM / 128)) * 128, n0 = (swz % (NDIM / 128)) * 128;
    float xscale = scale_ptr[0];
    f32x4 acc[4][4];
#pragma unroll
    for (int i = 0; i < 4; ++i)
#pragma unroll
        for (int j = 0; j < 4; ++j) acc[i][j] = (f32x4){0.f, 0.f, 0.f, 0.f};
    const int lrow = lane & 15, lk = (lane >> 4) * 8;
    for (int kt = 0; kt < KDIM; kt += 64) {
#pragma unroll
        for (int it = 0; it < 4; ++it) {
            int chunk = it * 256 + tid;
            int row = chunk >> 3, col = (chunk & 7) << 3;
            const f32x4* gA = (const f32x4*)(Af + (size_t)(m0 + row) * KDIM + kt + col);
            const f32x4* gB = (const f32x4*)(Btf + (size_t)(n0 + row) * KDIM + kt + col);
            f32x4 a0 = gA[0], a1 = gA[1], b0 = gB[0], b1 = gB[1];
            short8 ao, bo;
#pragma unroll
            for (int j = 0; j < 4; ++j) {
                ao[j] = f32_to_bf16(a0[j] * xscale); ao[j + 4] = f32_to_bf16(a1[j] * xscale);
                bo[j] = f32_to_bf16(b0[j]);          bo[j + 4] = f32_to_bf16(b1[j]);
            }
            *(short8*)(As + chunk * 8) = ao;
            *(short8*)(Bs + chunk * 8) = bo;
        }
        __syncthreads();
#pragma unroll
        for (int ks = 0; ks < 2; ++ks) {
            short8 af[4], bf[4];
#pragma unroll
            for (int mi = 0; mi < 4; ++mi)
                af[mi] = *(const short8*)(As + (wr * 64 + mi * 16 + lrow) * 64 + ks * 32 + lk);
#pragma unroll
            for (int ni = 0; ni < 4; ++ni)
                bf[ni] = *(const short8*)(Bs + (wc * 64 + ni * 16 + lrow) * 64 + ks * 32 + lk);
#pragma unroll
            for (int mi = 0; mi < 4; ++mi)
#pragma unroll
                for (int ni = 0; ni < 4; ++ni)
                    acc[mi][ni] = __builtin_amdgcn_mfma_f32_16x16x32_bf16(af[mi], bf[ni], acc[mi][ni], 0, 0, 0);
        }
        __syncthreads();
    }
    const int crow = (lane >> 4) * 4, ccol = lane & 15;
#pragma unroll
    for (int ni = 0; ni < 4; ++ni) {
        int col = n0 + wc * 64 + ni * 16 + ccol;
        float bv = bias[col];
#pragma unroll
        for (int mi = 0; mi < 4; ++mi) {
            int row = m0 + wr * 64 + mi * 16 + crow;
#pragma unroll
            for (int r = 0; r < 4; ++r)
                C[(size_t)(row + r) * NDIM + col] = acc[mi][ni][r] + bv;
        }
    }
}

extern "C" void kernel_launch(void* const* d_in, const int* in_sizes, int n_in,
                              void* d_out, int out_size, void* d_ws, size_t ws_size,
                              hipStream_t stream) {
    const float* x     = (const float*)d_in[0];
    const float* w     = (const float*)d_in[1];
    const float* scale = (const float*)d_in[2];
    const float* bias  = (const float*)d_in[3];
    float* out = (float*)d_out;

    const long long xN = (long long)MDIM * KDIM;
    const long long wN = (long long)NDIM * KDIM;
    const size_t needed = (size_t)(xN + wN) * sizeof(short);

    if (ws_size >= needed) {
        short* xb = (short*)d_ws;
        short* wb = xb + xN;
        cvt_all<<<2048, 256, 0, stream>>>(x, w, scale, xb, wb);
        dim3 grid((MDIM / BM) * (NDIM / BN));   // 2048
        gemm256_bf16_bt_bias<<<grid, THREADS, 0, stream>>>(xb, wb, bias, out);
    } else {
        dim3 grid((MDIM / 128) * (NDIM / 128));
        gemm_fused128<<<grid, 256, 0, stream>>>(x, w, scale, bias, out);
    }
}